// Round 5
// baseline (534.946 us; speedup 1.0000x reference)
//
#include <hip/hip_runtime.h>
#include <hip/hip_bf16.h>
#include <stdint.h>

typedef __bf16 bf16x8 __attribute__((ext_vector_type(8)));
typedef float f32x4 __attribute__((ext_vector_type(4)));
typedef unsigned short u16x8 __attribute__((ext_vector_type(8)));

#define AS1 __attribute__((address_space(1)))
#define AS3 __attribute__((address_space(3)))

__constant__ float c_nf4[16] = {
    -1.0f, -0.6961928009986877f, -0.5250730514526367f, -0.39491748809814453f,
    -0.28444138169288635f, -0.18477343022823334f, -0.09105003625154495f, 0.0f,
    0.07958029955625534f, 0.16093020141124725f, 0.24611230194568634f,
    0.33791524171829224f, 0.44070982933044434f, 0.5626170039176941f,
    0.7229568362236023f, 1.0f};

__device__ __forceinline__ unsigned short f2bf_rne(float f) {
  unsigned int u = __builtin_bit_cast(unsigned int, f);
  u += 0x7FFFu + ((u >> 16) & 1u);
  return (unsigned short)(u >> 16);
}

__global__ __launch_bounds__(256) void k_dequant_fold(
    const int* __restrict__ q, const float* __restrict__ scale,
    const float* __restrict__ lA, const float* __restrict__ lB,
    unsigned short* __restrict__ w, int IN, int shIN, int R, long total8) {
  long idx = (long)blockIdx.x * 256 + threadIdx.x;
  if (idx >= total8) return;
  long e0 = idx * 8;
  int o = (int)(e0 >> shIN);
  int i0 = (int)(e0 & (IN - 1));
  float s = scale[e0 >> 6];
  const int* qp = q + e0;
  int4 qa = *(const int4*)qp;
  int4 qb = *(const int4*)(qp + 4);
  float v[8];
  v[0] = c_nf4[qa.x & 15] * s; v[1] = c_nf4[qa.y & 15] * s;
  v[2] = c_nf4[qa.z & 15] * s; v[3] = c_nf4[qa.w & 15] * s;
  v[4] = c_nf4[qb.x & 15] * s; v[5] = c_nf4[qb.y & 15] * s;
  v[6] = c_nf4[qb.z & 15] * s; v[7] = c_nf4[qb.w & 15] * s;
  for (int r = 0; r < R; ++r) {
    float br = 4.0f * lB[o * R + r];
    const float* ap = lA + (long)r * IN + i0;
    float4 a0 = *(const float4*)ap;
    float4 a1 = *(const float4*)(ap + 4);
    v[0] += br * a0.x; v[1] += br * a0.y; v[2] += br * a0.z; v[3] += br * a0.w;
    v[4] += br * a1.x; v[5] += br * a1.y; v[6] += br * a1.z; v[7] += br * a1.w;
  }
  u16x8 pk;
#pragma unroll
  for (int j = 0; j < 8; ++j) pk[j] = f2bf_rne(v[j]);
  *(u16x8*)(w + e0) = pk;
}

// ---------------------------------------------------------------------------
// 256x256 tile, BK=64, 8 waves (2M x 4N), 4 phases/tile (T2+T3+T4+T5).
// A staged from f32 x via reg-stage (float4 loads -> cvt -> swizzled
// ds_write_b128); B staged via counted global_load_lds. Persistent blocks:
// grid = ntiles/2, each block runs 2 output tiles; pass-1 prologue loads
// issue before pass-0's epilogue so HBM latency hides under the stores.
// vmcnt(0) at pass start prevents stale tail-stage vs new-stage LDS race.
// ---------------------------------------------------------------------------
__global__ __launch_bounds__(512, 2) void k_gemm_256(
    const float* __restrict__ X, const unsigned short* __restrict__ Wb,
    const float* __restrict__ bias, float* __restrict__ out,
    int M, int N, int K, int npass) {
  __shared__ char smem[131072];
  const int tid = threadIdx.x;
  const int wid = tid >> 6;
  const int lane = tid & 63;
  const int wr = wid >> 2;
  const int wc = wid & 3;
  const int wcl = wc & 1;
  const int l15 = lane & 15;
  const int l16 = lane >> 4;

  // reader swizzle decomposition: (kk*64 + l16*16) ^ ((l15&7)<<4)
  const int kflip = (l15 & 4) ? 64 : 0;
  const int lowx = ((l16 ^ (l15 & 3)) << 4);
  const int baseA0 = wr * 16384 + l15 * 128 + lowx + kflip;
  const int baseA1 = wr * 16384 + l15 * 128 + lowx + (64 ^ kflip);
  const int baseB0 = 65536 + (wc >> 1) * 16384 + wcl * 8192 + l15 * 128 + lowx + kflip;
  const int baseB1 = baseB0 + (64 ^ kflip) - kflip;

  // A reg-stage chunk constants: 4 chunks x 16B bf16 (= 8 f32) per thread
  int ldsoffA[4], rowA[4], colA[4];
#pragma unroll
  for (int c = 0; c < 4; ++c) {
    const int h = c >> 1, j = c & 1;
    const int lo = wid * 2048 + j * 1024 + lane * 16;  // linear byte in 16KB half
    const int row = lo >> 7;
    ldsoffA[c] = h * 16384 + (lo ^ ((row & 7) << 4));
    rowA[c] = h * 128 + row;
    colA[c] = (lo & 127) >> 1;  // f32 element offset within K-tile
  }

  // B staging (global_load_lds, pre-swizzled source)
  int rowj[2], gcj[2];
#pragma unroll
  for (int j = 0; j < 2; ++j) {
    const int lo = wid * 2048 + j * 1024 + lane * 16;
    const int row = lo >> 7;
    const int ls = lo ^ ((row & 7) << 4);
    rowj[j] = row;
    gcj[j] = (ls & 127) >> 1;
  }
  const size_t halfstep = (size_t)128 * K;

  const float* pXA[4];
  const unsigned short* pSB0[2];
  const unsigned short* pSB1[2];

#define ST_B(bufl, h, coff)                                                          \
  {                                                                                  \
    __builtin_amdgcn_global_load_lds((const AS1 void*)(pSB##h[0] + (coff)),          \
        (AS3 void*)(smem + 65536 + (bufl) * 32768 + (h) * 16384 + wid * 2048),       \
        16, 0, 0);                                                                   \
    __builtin_amdgcn_global_load_lds((const AS1 void*)(pSB##h[1] + (coff)),          \
        (AS3 void*)(smem + 65536 + (bufl) * 32768 + (h) * 16384 + wid * 2048 + 1024),\
        16, 0, 0);                                                                   \
  }
#define LD_A(dst, coff)                                                              \
  {                                                                                  \
    _Pragma("unroll") for (int c = 0; c < 4; ++c) {                                  \
      dst[c][0] = *(const float4*)(pXA[c] + (coff));                                 \
      dst[c][1] = *(const float4*)(pXA[c] + (coff) + 4);                             \
    }                                                                                \
    __builtin_amdgcn_sched_barrier(0);                                               \
  }
#define CW_A(bufl, src)                                                              \
  _Pragma("unroll") for (int c = 0; c < 4; ++c) {                                    \
    bf16x8 wv;                                                                       \
    wv[0] = (__bf16)src[c][0].x; wv[1] = (__bf16)src[c][0].y;                        \
    wv[2] = (__bf16)src[c][0].z; wv[3] = (__bf16)src[c][0].w;                        \
    wv[4] = (__bf16)src[c][1].x; wv[5] = (__bf16)src[c][1].y;                        \
    wv[6] = (__bf16)src[c][1].z; wv[7] = (__bf16)src[c][1].w;                        \
    *(bf16x8*)(smem + (bufl) * 32768 + ldsoffA[c]) = wv;                             \
  }

  float4 fa[4][2], fa2[4][2];
  bf16x8 af[4][2], b0[2][2], b1[2][2];
  f32x4 acc[8][4];
#pragma unroll
  for (int i = 0; i < 8; ++i)
#pragma unroll
    for (int j = 0; j < 4; ++j) acc[i][j] = (f32x4)0.0f;

#define RD_A(bufl, mq)                                                               \
  _Pragma("unroll") for (int ii = 0; ii < 4; ++ii) {                                 \
    af[ii][0] = *(const bf16x8*)(smem + baseA0 +                                     \
                                 ((bufl) * 32768 + (mq) * 8192 + ii * 2048));        \
    af[ii][1] = *(const bf16x8*)(smem + baseA1 +                                     \
                                 ((bufl) * 32768 + (mq) * 8192 + ii * 2048));        \
  }
#define RD_B(bufl, q, arr)                                                           \
  _Pragma("unroll") for (int jj = 0; jj < 2; ++jj) {                                 \
    arr[jj][0] = *(const bf16x8*)(smem + baseB0 +                                    \
                                  ((bufl) * 32768 + (q) * 4096 + jj * 2048));        \
    arr[jj][1] = *(const bf16x8*)(smem + baseB1 +                                    \
                                  ((bufl) * 32768 + (q) * 4096 + jj * 2048));        \
  }
#define MFMA_Q(mq, q, arr)                                                           \
  _Pragma("unroll") for (int kk = 0; kk < 2; ++kk)                                   \
  _Pragma("unroll") for (int ii = 0; ii < 4; ++ii)                                   \
  _Pragma("unroll") for (int jj = 0; jj < 2; ++jj)                                   \
      acc[(mq)*4+ii][(q)*2+jj] = __builtin_amdgcn_mfma_f32_16x16x32_bf16(            \
          af[ii][kk], arr[jj][kk], acc[(mq)*4+ii][(q)*2+jj], 0, 0, 0);

#define BAR __builtin_amdgcn_s_barrier()
#define PRIO1 __builtin_amdgcn_s_setprio(1)
#define PRIO0 __builtin_amdgcn_s_setprio(0)
#define LGK0                                               \
  {                                                        \
    asm volatile("s_waitcnt lgkmcnt(0)" ::: "memory");     \
    __builtin_amdgcn_sched_barrier(0);                     \
  }
#define VM4 asm volatile("s_waitcnt vmcnt(4)" ::: "memory")
#define VM0 asm volatile("s_waitcnt vmcnt(0)" ::: "memory")

#define SUBTILE(bufl, SC)                                                            \
  /* p0 */                                                                           \
  RD_A(bufl, 0)                                                                      \
  BAR; LGK0; PRIO1; MFMA_Q(0, 0, b0) PRIO0; BAR;                                     \
  /* p1 */                                                                           \
  RD_B(bufl, 1, b1)                                                                  \
  BAR; LGK0; PRIO1; MFMA_Q(0, 1, b1) PRIO0; BAR;                                     \
  /* p2: A f32 loads first (vmcnt order), then B stages */                           \
  RD_A(bufl, 1)                                                                      \
  LD_A(fa, SC)                                                                       \
  ST_B(bufl, 0, SC) ST_B(bufl, 1, SC)                                                \
  BAR; LGK0; PRIO1; MFMA_Q(1, 0, b0) PRIO0; BAR;                                     \
  /* p3: drain f32 (leave 4 B-stages), cvt+swizzled ds_write, publish */             \
  VM4;                                                                               \
  CW_A(bufl, fa)                                                                     \
  asm volatile("s_waitcnt lgkmcnt(0)" ::: "memory");                                 \
  __builtin_amdgcn_sched_barrier(0);                                                 \
  BAR; PRIO1; MFMA_Q(1, 1, b1) PRIO0;                                                \
  RD_B((bufl) ^ 1, 0, b0)                                                            \
  BAR;

#define EPI(m0e, n0e)                                                                \
  _Pragma("unroll") for (int nf = 0; nf < 4; ++nf) {                                 \
    const int col = (n0e) + wc * 64 + nf * 16 + l15;                                 \
    const float bv = bias[col];                                                      \
    _Pragma("unroll") for (int mi = 0; mi < 8; ++mi) {                               \
      const int row = (m0e) + wr * 128 + mi * 16 + l16 * 4;                          \
      _Pragma("unroll") for (int j = 0; j < 4; ++j)                                  \
          out[(size_t)(row + j) * N + col] = acc[mi][nf][j] + bv;                    \
    }                                                                                \
  }

  const int NT = K >> 6;
  const int nbn = N >> 8;
  const int nwgv = gridDim.x * npass;
  const bool doswz = (nwgv & 7) == 0;
  const int cpx = nwgv >> 3;
  int prevm = 0, prevn = 0;

  for (int pass = 0; pass < npass; ++pass) {
    int vid = blockIdx.x + pass * gridDim.x;
    if (doswz) vid = (vid & 7) * cpx + (vid >> 3);
    const int m0 = (vid / nbn) << 8;
    const int n0 = (vid % nbn) << 8;

#pragma unroll
    for (int c = 0; c < 4; ++c)
      pXA[c] = X + (size_t)(m0 + rowA[c]) * K + colA[c];
#pragma unroll
    for (int j = 0; j < 2; ++j) {
      pSB0[j] = Wb + (size_t)(n0 + rowj[j]) * K + gcj[j];
      pSB1[j] = pSB0[j] + halfstep;
    }

    // drain any tail dummy-stages from previous pass before re-staging same LDS
    VM0;
    // prologue: tiles 0,1 of this pass
    LD_A(fa, 0)
    ST_B(0, 0, 0) ST_B(0, 1, 0)
    LD_A(fa2, 64)
    ST_B(1, 0, 64) ST_B(1, 1, 64)
    CW_A(0, fa)
    CW_A(1, fa2)
    asm volatile("s_waitcnt lgkmcnt(0)" ::: "memory");
    if (pass) {
      EPI(prevm, prevn)
#pragma unroll
      for (int i = 0; i < 8; ++i)
#pragma unroll
        for (int j = 0; j < 4; ++j) acc[i][j] = (f32x4)0.0f;
    }
    VM0;
    __builtin_amdgcn_sched_barrier(0);
    BAR;
    RD_B(0, 0, b0)
#pragma unroll
    for (int c = 0; c < 4; ++c) pXA[c] += 128;
#pragma unroll
    for (int j = 0; j < 2; ++j) { pSB0[j] += 128; pSB1[j] += 128; }

    for (int t = 0; t < NT; t += 2) {
      SUBTILE(0, 0)
      SUBTILE(1, 64)
      if (t + 4 < NT) {
#pragma unroll
        for (int c = 0; c < 4; ++c) pXA[c] += 128;
#pragma unroll
        for (int j = 0; j < 2; ++j) { pSB0[j] += 128; pSB1[j] += 128; }
      }
    }
    prevm = m0; prevn = n0;
  }

  EPI(prevm, prevn)

#undef ST_B
#undef LD_A
#undef CW_A
#undef RD_A
#undef RD_B
#undef MFMA_Q
#undef BAR
#undef PRIO1
#undef PRIO0
#undef LGK0
#undef VM4
#undef VM0
#undef SUBTILE
#undef EPI
}

extern "C" void kernel_launch(void* const* d_in, const int* in_sizes, int n_in,
                              void* d_out, int out_size, void* d_ws, size_t ws_size,
                              hipStream_t stream) {
  const float* x = (const float*)d_in[0];
  const int* qw = (const int*)d_in[1];
  const float* qs = (const float*)d_in[2];
  const float* bias = (const float*)d_in[3];
  const float* lA = (const float*)d_in[4];
  const float* lB = (const float*)d_in[5];
  float* out = (float*)d_out;

  const int OUT = in_sizes[3];
  const long qn = (long)in_sizes[1];
  const int IN = (int)(qn / OUT);
  const int R = in_sizes[5] / OUT;
  const long xn = (long)in_sizes[0];
  const int M = (int)(xn / IN);
  const int N = OUT, K = IN;

  unsigned short* Wb = (unsigned short*)d_ws;   // OUT*IN bf16

  const int shIN = 31 - __builtin_clz((unsigned)IN);

  const long w8 = qn / 8;
  k_dequant_fold<<<(int)((w8 + 255) / 256), 256, 0, stream>>>(qw, qs, lA, lB, Wb, IN, shIN, R, w8);

  const int ntiles = (M / 256) * (N / 256);
  const int npass = ((ntiles & 1) == 0) ? 2 : 1;
  dim3 grid(ntiles / npass);
  k_gemm_256<<<grid, 512, 0, stream>>>(x, Wb, bias, out, M, N, K, npass);
}

// Round 6
// 292.060 us; speedup vs baseline: 1.8316x; 1.8316x over previous
//
#include <hip/hip_runtime.h>
#include <hip/hip_bf16.h>
#include <stdint.h>

typedef __bf16 bf16x8 __attribute__((ext_vector_type(8)));
typedef float f32x4 __attribute__((ext_vector_type(4)));
typedef unsigned short u16x8 __attribute__((ext_vector_type(8)));

#define AS1 __attribute__((address_space(1)))
#define AS3 __attribute__((address_space(3)))

__constant__ float c_nf4[16] = {
    -1.0f, -0.6961928009986877f, -0.5250730514526367f, -0.39491748809814453f,
    -0.28444138169288635f, -0.18477343022823334f, -0.09105003625154495f, 0.0f,
    0.07958029955625534f, 0.16093020141124725f, 0.24611230194568634f,
    0.33791524171829224f, 0.44070982933044434f, 0.5626170039176941f,
    0.7229568362236023f, 1.0f};

__device__ __forceinline__ unsigned short f2bf_rne(float f) {
  unsigned int u = __builtin_bit_cast(unsigned int, f);
  u += 0x7FFFu + ((u >> 16) & 1u);
  return (unsigned short)(u >> 16);
}

// Fused prep: blocks [0, wb) dequant+LoRA-fold W; blocks [wb, wb+xb) cvt x.
__global__ __launch_bounds__(256) void k_prep(
    const int* __restrict__ q, const float* __restrict__ scale,
    const float* __restrict__ lA, const float* __restrict__ lB,
    const float* __restrict__ x, unsigned short* __restrict__ w,
    unsigned short* __restrict__ xb, int IN, int shIN, int R,
    long w8, long x8) {
  long idx = (long)blockIdx.x * 256 + threadIdx.x;
  if (idx < w8) {
    long e0 = idx * 8;
    int o = (int)(e0 >> shIN);
    int i0 = (int)(e0 & (IN - 1));
    float s = scale[e0 >> 6];
    const int* qp = q + e0;
    int4 qa = *(const int4*)qp;
    int4 qb = *(const int4*)(qp + 4);
    float v[8];
    v[0] = c_nf4[qa.x & 15] * s; v[1] = c_nf4[qa.y & 15] * s;
    v[2] = c_nf4[qa.z & 15] * s; v[3] = c_nf4[qa.w & 15] * s;
    v[4] = c_nf4[qb.x & 15] * s; v[5] = c_nf4[qb.y & 15] * s;
    v[6] = c_nf4[qb.z & 15] * s; v[7] = c_nf4[qb.w & 15] * s;
    for (int r = 0; r < R; ++r) {
      float br = 4.0f * lB[o * R + r];
      const float* ap = lA + (long)r * IN + i0;
      float4 a0 = *(const float4*)ap;
      float4 a1 = *(const float4*)(ap + 4);
      v[0] += br * a0.x; v[1] += br * a0.y; v[2] += br * a0.z; v[3] += br * a0.w;
      v[4] += br * a1.x; v[5] += br * a1.y; v[6] += br * a1.z; v[7] += br * a1.w;
    }
    u16x8 pk;
#pragma unroll
    for (int j = 0; j < 8; ++j) pk[j] = f2bf_rne(v[j]);
    *(u16x8*)(w + e0) = pk;
  } else {
    long i2 = idx - w8;
    if (i2 >= x8) return;
    long e0 = i2 * 8;
    float4 a0 = *(const float4*)(x + e0);
    float4 a1 = *(const float4*)(x + e0 + 4);
    u16x8 pk;
    pk[0] = f2bf_rne(a0.x); pk[1] = f2bf_rne(a0.y);
    pk[2] = f2bf_rne(a0.z); pk[3] = f2bf_rne(a0.w);
    pk[4] = f2bf_rne(a1.x); pk[5] = f2bf_rne(a1.y);
    pk[6] = f2bf_rne(a1.z); pk[7] = f2bf_rne(a1.w);
    *(u16x8*)(xb + e0) = pk;
  }
}

// ---------------------------------------------------------------------------
// 256x256 tile, BK=64, 8 waves (2M x 4N), 4 phases/tile (T2+T3+T4+T5).
// Reads-early schedule: each phase = [lgkm-wait; MFMA; NEXT ops; BAR] so
// ds_read issue+latency overlaps barrier convergence and the co-resident
// wave's MFMA. Race discipline: a region's stage issues >=1 barrier after
// that region's reads completed (lgkm0 precedes the phase's trailing BAR);
// VM4 before p2's BAR so p3's next-buf pre-reads follow an all-wave drain.
// ---------------------------------------------------------------------------
__global__ __launch_bounds__(512, 2) void k_gemm_256(
    const unsigned short* __restrict__ Xb, const unsigned short* __restrict__ Wb,
    const float* __restrict__ bias, float* __restrict__ out,
    int M, int N, int K) {
  __shared__ char smem[131072];
  const int tid = threadIdx.x;
  const int wid = tid >> 6;
  const int lane = tid & 63;
  const int wr = wid >> 2;
  const int wc = wid & 3;
  const int wcl = wc & 1;
  const int l15 = lane & 15;
  const int l16 = lane >> 4;

  // reader swizzle decomposition: (kk*64 + l16*16) ^ ((l15&7)<<4)
  const int kflip = (l15 & 4) ? 64 : 0;
  const int lowx = ((l16 ^ (l15 & 3)) << 4);
  const int baseA0 = wr * 16384 + l15 * 128 + lowx + kflip;
  const int baseA1 = wr * 16384 + l15 * 128 + lowx + (64 ^ kflip);
  const int baseB0 = 65536 + (wc >> 1) * 16384 + wcl * 8192 + l15 * 128 + lowx + kflip;
  const int baseB1 = baseB0 + (64 ^ kflip) - kflip;

  int bid = blockIdx.x;
  const int nwg = gridDim.x;
  if ((nwg & 7) == 0) { const int cpx = nwg >> 3; bid = (bid & 7) * cpx + (bid >> 3); }
  const int nbn = N >> 8;
  const int m0 = (bid / nbn) << 8;
  const int n0 = (bid % nbn) << 8;

  // per-lane pre-swizzled global source offsets for staging
  int rowj[2], gcj[2];
#pragma unroll
  for (int j = 0; j < 2; ++j) {
    const int lo = wid * 2048 + j * 1024 + lane * 16;
    const int row = lo >> 7;
    const int ls = lo ^ ((row & 7) << 4);
    rowj[j] = row;
    gcj[j] = (ls & 127) >> 1;
  }
  const size_t halfstep = (size_t)128 * K;
  const unsigned short* pSA0[2]; const unsigned short* pSA1[2];
  const unsigned short* pSB0[2]; const unsigned short* pSB1[2];
#pragma unroll
  for (int j = 0; j < 2; ++j) {
    pSA0[j] = Xb + (size_t)(m0 + rowj[j]) * K + gcj[j];
    pSA1[j] = pSA0[j] + halfstep;
    pSB0[j] = Wb + (size_t)(n0 + rowj[j]) * K + gcj[j];
    pSB1[j] = pSB0[j] + halfstep;
  }

#define ST_A(bufl, h, coff)                                                          \
  {                                                                                  \
    __builtin_amdgcn_global_load_lds((const AS1 void*)(pSA##h[0] + (coff)),          \
        (AS3 void*)(smem + (bufl) * 32768 + (h) * 16384 + wid * 2048), 16, 0, 0);    \
    __builtin_amdgcn_global_load_lds((const AS1 void*)(pSA##h[1] + (coff)),          \
        (AS3 void*)(smem + (bufl) * 32768 + (h) * 16384 + wid * 2048 + 1024),        \
        16, 0, 0);                                                                   \
  }
#define ST_B(bufl, h, coff)                                                          \
  {                                                                                  \
    __builtin_amdgcn_global_load_lds((const AS1 void*)(pSB##h[0] + (coff)),          \
        (AS3 void*)(smem + 65536 + (bufl) * 32768 + (h) * 16384 + wid * 2048),       \
        16, 0, 0);                                                                   \
    __builtin_amdgcn_global_load_lds((const AS1 void*)(pSB##h[1] + (coff)),          \
        (AS3 void*)(smem + 65536 + (bufl) * 32768 + (h) * 16384 + wid * 2048 + 1024),\
        16, 0, 0);                                                                   \
  }

  bf16x8 afA[4][2], afB[4][2], b0[2][2], b1[2][2];
  f32x4 acc[8][4];
#pragma unroll
  for (int i = 0; i < 8; ++i)
#pragma unroll
    for (int j = 0; j < 4; ++j) acc[i][j] = (f32x4)0.0f;

#define RD_A(bufl, mq, dst)                                                          \
  _Pragma("unroll") for (int ii = 0; ii < 4; ++ii) {                                 \
    dst[ii][0] = *(const bf16x8*)(smem + baseA0 +                                    \
                                  ((bufl) * 32768 + (mq) * 8192 + ii * 2048));       \
    dst[ii][1] = *(const bf16x8*)(smem + baseA1 +                                    \
                                  ((bufl) * 32768 + (mq) * 8192 + ii * 2048));       \
  }
#define RD_B(bufl, q, arr)                                                           \
  _Pragma("unroll") for (int jj = 0; jj < 2; ++jj) {                                 \
    arr[jj][0] = *(const bf16x8*)(smem + baseB0 +                                    \
                                  ((bufl) * 32768 + (q) * 4096 + jj * 2048));        \
    arr[jj][1] = *(const bf16x8*)(smem + baseB1 +                                    \
                                  ((bufl) * 32768 + (q) * 4096 + jj * 2048));        \
  }
#define MFMA_Q(mq, q, A, arr)                                                        \
  _Pragma("unroll") for (int kk = 0; kk < 2; ++kk)                                   \
  _Pragma("unroll") for (int ii = 0; ii < 4; ++ii)                                   \
  _Pragma("unroll") for (int jj = 0; jj < 2; ++jj)                                   \
      acc[(mq)*4+ii][(q)*2+jj] = __builtin_amdgcn_mfma_f32_16x16x32_bf16(            \
          A[ii][kk], arr[jj][kk], acc[(mq)*4+ii][(q)*2+jj], 0, 0, 0);

#define BAR __builtin_amdgcn_s_barrier()
#define PRIO1 __builtin_amdgcn_s_setprio(1)
#define PRIO0 __builtin_amdgcn_s_setprio(0)
#define LGK0                                               \
  {                                                        \
    asm volatile("s_waitcnt lgkmcnt(0)" ::: "memory");     \
    __builtin_amdgcn_sched_barrier(0);                     \
  }
#define VM4 asm volatile("s_waitcnt vmcnt(4)" ::: "memory")
#define VM8 asm volatile("s_waitcnt vmcnt(8)" ::: "memory")

  // Reads-early subtile: phase = [wait; MFMA; next-phase ops; BAR]
#define SUBTILE(bufl, SC)                                                            \
  /* p0 */                                                                           \
  LGK0; PRIO1; MFMA_Q(0, 0, afA, b0) PRIO0;                                          \
  RD_B(bufl, 1, b1)                                                                  \
  BAR;                                                                               \
  /* p1 */                                                                           \
  LGK0; PRIO1; MFMA_Q(0, 1, afA, b1) PRIO0;                                          \
  RD_A(bufl, 1, afB)                                                                 \
  BAR;                                                                               \
  /* p2: B of bufl fully consumed (b1 done p1-LGK0) -> stage B(t+2) */               \
  LGK0; PRIO1; MFMA_Q(1, 0, afB, b0) PRIO0;                                          \
  ST_B(bufl, 0, SC) ST_B(bufl, 1, SC)                                                \
  VM4;                                                                               \
  BAR;                                                                               \
  /* p3: A of bufl consumed -> stage A(t+2); pre-read next tile's afA,b0 */          \
  PRIO1; MFMA_Q(1, 1, afB, b1) PRIO0;                                                \
  ST_A(bufl, 0, SC) ST_A(bufl, 1, SC)                                                \
  RD_A((bufl) ^ 1, 0, afA)                                                           \
  RD_B((bufl) ^ 1, 0, b0)                                                            \
  BAR;

  const int NT = K >> 6;

  // prologue: stage tile0->buf0, tile1->buf1; drain tile0; pre-read afA,b0
  ST_A(0, 0, 0) ST_A(0, 1, 0) ST_B(0, 0, 0) ST_B(0, 1, 0)
  ST_A(1, 0, 64) ST_A(1, 1, 64) ST_B(1, 0, 64) ST_B(1, 1, 64)
  VM8;
  BAR;
  RD_A(0, 0, afA)
  RD_B(0, 0, b0)
#pragma unroll
  for (int j = 0; j < 2; ++j) { pSA0[j] += 128; pSA1[j] += 128; pSB0[j] += 128; pSB1[j] += 128; }

  for (int t = 0; t < NT; t += 2) {
    SUBTILE(0, 0)
    SUBTILE(1, 64)
    if (t + 4 < NT) {
#pragma unroll
      for (int j = 0; j < 2; ++j) { pSA0[j] += 128; pSA1[j] += 128; pSB0[j] += 128; pSB1[j] += 128; }
    }
  }

  // epilogue: C/D layout col=lane&15, row=(lane>>4)*4+j
#pragma unroll
  for (int nf = 0; nf < 4; ++nf) {
    const int col = n0 + wc * 64 + nf * 16 + l15;
    const float bv = bias[col];
#pragma unroll
    for (int mi = 0; mi < 8; ++mi) {
      const int row = m0 + wr * 128 + mi * 16 + l16 * 4;
#pragma unroll
      for (int j = 0; j < 4; ++j)
        out[(size_t)(row + j) * N + col] = acc[mi][nf][j] + bv;
    }
  }
#undef ST_A
#undef ST_B
#undef RD_A
#undef RD_B
#undef MFMA_Q
#undef BAR
#undef PRIO1
#undef PRIO0
#undef LGK0
#undef VM4
#undef VM8
#undef SUBTILE
}

extern "C" void kernel_launch(void* const* d_in, const int* in_sizes, int n_in,
                              void* d_out, int out_size, void* d_ws, size_t ws_size,
                              hipStream_t stream) {
  const float* x = (const float*)d_in[0];
  const int* qw = (const int*)d_in[1];
  const float* qs = (const float*)d_in[2];
  const float* bias = (const float*)d_in[3];
  const float* lA = (const float*)d_in[4];
  const float* lB = (const float*)d_in[5];
  float* out = (float*)d_out;

  const int OUT = in_sizes[3];
  const long qn = (long)in_sizes[1];
  const int IN = (int)(qn / OUT);
  const int R = in_sizes[5] / OUT;
  const long xn = (long)in_sizes[0];
  const int M = (int)(xn / IN);
  const int N = OUT, K = IN;

  unsigned short* Wb = (unsigned short*)d_ws;   // OUT*IN bf16
  unsigned short* Xb = Wb + qn;                 // M*IN bf16

  const int shIN = 31 - __builtin_clz((unsigned)IN);

  const long w8 = qn / 8;
  const long x8 = xn / 8;
  const long nchunks = w8 + x8;
  k_prep<<<(int)((nchunks + 255) / 256), 256, 0, stream>>>(
      qw, qs, lA, lB, x, Wb, Xb, IN, shIN, R, w8, x8);

  dim3 grid((M / 256) * (N / 256));
  k_gemm_256<<<grid, 512, 0, stream>>>(Xb, Wb, bias, out, M, N, K);
}